// Round 16
// baseline (131.934 us; speedup 1.0000x reference)
//
#include <hip/hip_runtime.h>
#include <hip/hip_bf16.h>
#include <math.h>

#ifndef M_PI
#define M_PI 3.14159265358979323846
#endif

#define T 2048
#define EDGE 256
#define TT 1536            // trimmed timesteps
#define PHA_N 50
#define AMP_N 30
#define NBANDS 80
#define NBINS 18
#define NBC 16             // B*C = 2*8
#define FMAX 768           // forward DFT bins stored [0, FMAX); max needed bin = 634
#define NCH 16             // t-chunks for forward DFT
#define CHLEN (T / NCH)    // 128
#define NW 12              // f-chunks per band block
#define CS 53              // f-steps per chunk (12*53 = 636 >= 634)
#define TW 32              // t's per band block (R15: 64 -> 32 for 3 blocks/CU)
#define TPB (NW * TW)      // 384 threads (6 waves; each wave = 2 f-chunks)
#define NEV (2 * NBANDS)   // 160 snapshot events

typedef __attribute__((ext_vector_type(8))) short short8;       // 8x16-bit
typedef __attribute__((ext_vector_type(8))) _Float16 half8;     // 8 f16 (4 VGPRs)
typedef __attribute__((ext_vector_type(16))) float float16;     // 32x32 C/D frag

// Inclusive frequency-bin range [fl, fh] for a band, replicating the
// reference's float32 band edges vs exact quarter-Hz freq grid.
__device__ __forceinline__ void band_range(int band, int* fl, int* fh) {
    double lo, hi;
    if (band < PHA_N) {
        double mid = 2.0 + (double)band * (18.0 / 49.0);   // linspace(2,20,50)
        lo = (double)(float)(mid * 0.75);
        hi = (double)(float)(mid * 1.25);
    } else {
        int j = band - PHA_N;
        double mid = 60.0 + (double)j * (81.0 / 29.0);     // linspace(60,141,30)
        lo = (double)(float)(mid * 0.875);
        hi = (double)(float)(mid * 1.125);
    }
    int l = (int)ceil(lo * 4.0);     // freq = 0.25*f ; f >= 4*lo
    int h = (int)floor(hi * 4.0);    // f <= 4*hi
    if (l < 1) l = 1;
    if (h > FMAX - 1) h = FMAX - 1;
    *fl = l; *fh = h;
}

// Kernel A: chunked forward DFT partials (fp64). Two independent 64-step
// oscillator chains per thread; Xp layout ch-slowest for coalesced writes.
__global__ void dft_kernel(const float* __restrict__ x, double* __restrict__ Xp) {
    __shared__ float xs[CHLEN];
    const int bc = blockIdx.x;
    const int fb = blockIdx.y;
    const int ch = blockIdx.z;
    const int tid = threadIdx.x;
    const int t0 = ch * CHLEN;
    if (tid < CHLEN) xs[tid] = x[bc * T + t0 + tid];
    __syncthreads();
    const int f = fb * 256 + tid;
    const double om = 2.0 * M_PI / (double)T;
    double s, c;
    sincos(om * (double)(f & (T - 1)), &s, &c);
    const double wR = c, wI = -s;                       // e^{-i om f}
    double curR[2], curI[2], accR[2], accI[2];
    #pragma unroll
    for (int h = 0; h < 2; ++h) {
        sincos(om * (double)((f * (t0 + h * 64)) & (T - 1)), &s, &c);
        curR[h] = c; curI[h] = -s;                      // e^{-i om f (t0+64h)}
        accR[h] = 0.0; accI[h] = 0.0;
    }
    #pragma unroll 2
    for (int t = 0; t < 64; ++t) {
        #pragma unroll
        for (int h = 0; h < 2; ++h) {
            double v = (double)xs[t + h * 64];
            accR[h] += v * curR[h];
            accI[h] += v * curI[h];
            double nR = curR[h] * wR - curI[h] * wI;
            double nI = curR[h] * wI + curI[h] * wR;
            curR[h] = nR; curI[h] = nI;
        }
    }
    const size_t o = (size_t)((ch * NBC + bc) * FMAX + f) * 2;
    Xp[o + 0] = accR[0] + accR[1];
    Xp[o + 1] = accI[0] + accI[1];
}

// Kernel A2: reduce NCH chunk partials -> float2 Xf[bc*FMAX+f]. Same fp64
// summation order as R15's in-band staging -> bit-identical downstream.
__global__ void reduce_kernel(const double* __restrict__ Xp, float2* __restrict__ Xf) {
    const int gid = blockIdx.x * 256 + threadIdx.x;   // 0..12287 = bc*FMAX+f
    double r = 0.0, im = 0.0;
    #pragma unroll
    for (int c = 0; c < NCH; ++c) {
        r  += Xp[((size_t)c * NBC * FMAX + gid) * 2 + 0];
        im += Xp[((size_t)c * NBC * FMAX + gid) * 2 + 1];
    }
    Xf[gid] = make_float2((float)r, (float)im);
}

// Kernel B: band synthesis via PREFIX SUM over frequency (R14 formulation,
// R15 occupancy fix: TW=32 -> ~52 KB LDS -> 3 blocks/CU; 768 blocks = exactly
// 3/CU, one balanced round; staging via pre-reduced float2 Xf).
// S_band = P[fh] - P[fl-1]; snapshots at the 160 boundary f's; chunk totals
// -> carries -> assembly (atan2f -> idx, sqrtf -> f16 Abuf).
__global__ __launch_bounds__(TPB)
void band_kernel(const float2* __restrict__ Xf,
                 unsigned char* __restrict__ idx_buf,
                 _Float16* __restrict__ Abuf) {
    __shared__ float sXr[640], sXi[640];          // staged Xf, index 1..634
    __shared__ float snapR[NEV][TW];              // prefix snapshots (40 KB)
    __shared__ float snapI[NEV][TW];
    __shared__ float totR[NW][TW], totI[NW][TW];  // chunk totals
    __shared__ float carR[NW][TW], carI[NW][TW];  // carries (sum of prev chunks)
    __shared__ int bfl[NBANDS], bfh[NBANDS];
    __shared__ int ef[NEV];                       // event f per slot
    __shared__ short srt_f[NEV];                  // events sorted by f
    __shared__ unsigned char srt_s[NEV];          // slot of sorted event
    __shared__ int cstart[NW];                    // first sorted-event idx per chunk
    const int bc = blockIdx.x;
    const int tg = blockIdx.y;                    // t-group (TW t's)
    const int tid = threadIdx.x;
    const int w = tid >> 5;                       // f-chunk 0..11 (half-wave)
    const int tl = tid & (TW - 1);
    const int t = tg * TW + tl + EDGE;            // absolute time index

    for (int i = tid; i < 634; i += TPB) {
        const float2 v = Xf[bc * FMAX + i + 1];
        sXr[i + 1] = v.x; sXi[i + 1] = v.y;
    }
    if (tid < NBANDS) { int fl, fh; band_range(tid, &fl, &fh); bfl[tid] = fl; bfh[tid] = fh; }
    if (tid < NW) cstart[tid] = NEV;
    __syncthreads();
    if (tid < NEV) ef[tid] = (tid & 1) ? bfh[tid >> 1] : bfl[tid >> 1] - 1;  // all >= 5
    __syncthreads();
    if (tid < NEV) {
        const int fe = ef[tid];
        int rank = 0;
        for (int j = 0; j < NEV; ++j) {          // broadcast reads, O(160)
            const int fj = ef[j];
            rank += (fj < fe || (fj == fe && j < tid)) ? 1 : 0;
        }
        srt_f[rank] = (short)fe;
        srt_s[rank] = (unsigned char)tid;
        atomicMin(&cstart[(fe - 1) / CS], rank); // native int LDS atomic [R8]
    }
    __syncthreads();

    // chunk-local prefix with snapshots at events (half-wave-uniform schedule)
    const int g0 = w * CS + 1;
    int ptr = cstart[w];
    int nf = (ptr < NEV) ? (int)srt_f[ptr] : 10000;
    const float omf = (float)(2.0 * M_PI / (double)T);
    float ss, cc;
    sincosf(omf * (float)(t & (T - 1)), &ss, &cc);          // step e^{i om t}
    float Er, Ei;
    { float s0, c0; sincosf(omf * (float)(((g0 - 1) * t) & (T - 1)), &s0, &c0);
      Er = c0; Ei = s0; }                                   // e^{i om (g0-1) t}
    float Pr = 0.0f, Pi = 0.0f;
    for (int step = 0; step < CS; ++step) {
        const int g = g0 + step;
        if (g > 634) break;
        const float nEr = Er * cc - Ei * ss;
        const float nEi = Er * ss + Ei * cc;
        Er = nEr; Ei = nEi;
        const float Xr = sXr[g], Xi = sXi[g];               // 2-addr broadcast
        Pr += Xr * Er - Xi * Ei;
        Pi += Xr * Ei + Xi * Er;
        while (g == nf) {                                   // rare (~13/chunk)
            const int slot = srt_s[ptr];
            snapR[slot][tl] = Pr;
            snapI[slot][tl] = Pi;
            ++ptr;
            nf = (ptr < NEV) ? (int)srt_f[ptr] : 10000;
        }
    }
    totR[w][tl] = Pr; totI[w][tl] = Pi;
    __syncthreads();
    {
        float cr = 0.0f, ci = 0.0f;
        for (int ww = 0; ww < w; ++ww) { cr += totR[ww][tl]; ci += totI[ww][tl]; }
        carR[w][tl] = cr; carI[w][tl] = ci;
    }
    __syncthreads();

    // assembly: band sum = (snap_hi + carry_hi) - (snap_lo + carry_lo)
    const float widthf = (float)(2.0 * M_PI / (double)NBINS);
    const float pif = (float)M_PI;
    for (int o = tid; o < NBANDS * TW; o += TPB) {
        const int band = o >> 5, ttl = o & (TW - 1);
        const int fl = bfl[band], fh = bfh[band];
        const int clo = (fl - 2) / CS;           // chunk of f = fl-1
        const int chi = (fh - 1) / CS;           // chunk of f = fh
        const float PloR = snapR[2 * band][ttl] + carR[clo][ttl];
        const float PloI = snapI[2 * band][ttl] + carI[clo][ttl];
        const float PhiR = snapR[2 * band + 1][ttl] + carR[chi][ttl];
        const float PhiI = snapI[2 * band + 1][ttl] + carI[chi][ttl];
        const float Sr = PhiR - PloR;
        const float Si = PhiI - PloI;
        const int trel = tg * TW + ttl;
        if (band < PHA_N) {
            float pha = atan2f(Si, Sr);                     // (-pi, pi]
            int b = (int)floorf((pha + pif) / widthf);
            if (b < 0) b = 0;
            if (b > NBINS - 1) b = NBINS - 1;
            idx_buf[(size_t)(bc * PHA_N + band) * TT + trel] = (unsigned char)b;
        } else {
            float amp = sqrtf(Sr * Sr + Si * Si) * (2.0f / (float)T);
            Abuf[(size_t)(bc * 32 + (band - PHA_N)) * TT + trel] = (_Float16)amp;
        }
    }
    if (tid < TW)   // ones (counts) row
        Abuf[(size_t)(bc * 32 + 30) * TT + tg * TW + tid] = (_Float16)1.0f;
}

// Kernel C: bin-sum as f16 MFMA matmul + inline MI epilogue (frozen since R12).
// Per (bc,p) block: C[31x18] = A[31x1536](f16 amp+ones) x Onehot[1536x18].
__global__ void mi_kernel(const unsigned char* __restrict__ idx_buf,
                          const _Float16* __restrict__ Abuf,
                          float* __restrict__ out) {
    __shared__ unsigned int sidx_s[TT / 4];       // 384 packed idx words
    __shared__ float cpart[4][32][NBINS];         // per-kquarter C partials
    const int blk = blockIdx.x;                   // bc*50 + p
    const int bc = blk / PHA_N;
    const int p = blk % PHA_N;
    const int tid = threadIdx.x;
    const int wave = tid >> 6;                    // k-quarter 0..3
    const int lane = tid & 63;

    for (int i = tid; i < TT / 4; i += 256)
        sidx_s[i] = ((const unsigned int*)(idx_buf + (size_t)(bc * PHA_N + p) * TT))[i];
    __syncthreads();

    const int n = lane & 31;                      // A row m == B col n == lane&31
    const int kq = lane >> 5;                     // k-quad: 0 or 1 (8 k's each)
    const half8* arow = (const half8*)(Abuf + (size_t)(bc * 32 + n) * TT
                                       + wave * 384 + kq * 8);
    float16 acc = {0.0f};
    #pragma unroll 4
    for (int ks = 0; ks < 24; ++ks) {
        const half8 a = arow[ks * 2];             // K-step stride = 16 f16 = 2 half8
        const int w0 = wave * 96 + ks * 4 + kq * 2;
        const unsigned int lo = sidx_s[w0];
        const unsigned int hi = sidx_s[w0 + 1];
        short8 bs;
        bs[0] = ((lo & 0xffu) == (unsigned)n) ? (short)0x3C00 : (short)0;   // f16 1.0
        bs[1] = (((lo >> 8) & 0xffu) == (unsigned)n) ? (short)0x3C00 : (short)0;
        bs[2] = (((lo >> 16) & 0xffu) == (unsigned)n) ? (short)0x3C00 : (short)0;
        bs[3] = ((lo >> 24) == (unsigned)n) ? (short)0x3C00 : (short)0;
        bs[4] = ((hi & 0xffu) == (unsigned)n) ? (short)0x3C00 : (short)0;
        bs[5] = (((hi >> 8) & 0xffu) == (unsigned)n) ? (short)0x3C00 : (short)0;
        bs[6] = (((hi >> 16) & 0xffu) == (unsigned)n) ? (short)0x3C00 : (short)0;
        bs[7] = ((hi >> 24) == (unsigned)n) ? (short)0x3C00 : (short)0;
        const half8 b = __builtin_bit_cast(half8, bs);
        acc = __builtin_amdgcn_mfma_f32_32x32x16_f16(a, b, acc, 0, 0, 0);
    }

    // scatter C frag to LDS (cols >= NBINS and row 31 discarded)
    if (n < NBINS) {
        #pragma unroll
        for (int r = 0; r < 16; ++r) {
            const int row = (r & 3) + 8 * (r >> 2) + 4 * kq;
            if (row < 31) cpart[wave][row][n] = acc[r];
        }
    }
    __syncthreads();

    // MI epilogue: thread a < 30 computes out[blk*30 + a]
    if (tid < AMP_N) {
        const int a = tid;
        double m[NBINS], tot = 0.0;
        #pragma unroll
        for (int k = 0; k < NBINS; ++k) {
            double cnt = (double)(cpart[0][30][k] + cpart[1][30][k]
                                + cpart[2][30][k] + cpart[3][30][k]);     // counts
            double denom = cnt > 1e-9 ? cnt : 1e-9;
            double s = (double)(cpart[0][a][k] + cpart[1][a][k]
                              + cpart[2][a][k] + cpart[3][a][k]);
            m[k] = s / denom;
            tot += m[k];
        }
        double dt = tot > 1e-9 ? tot : 1e-9;
        double accm = 0.0;
        #pragma unroll
        for (int k = 0; k < NBINS; ++k) {
            double pr = m[k] / dt;
            accm += pr * log(pr + 1e-9);
        }
        const double lognb = log((double)NBINS);
        out[(size_t)blk * AMP_N + a] = (float)((lognb + accm) / lognb);
    }
}

extern "C" void kernel_launch(void* const* d_in, const int* in_sizes, int n_in,
                              void* d_out, int out_size, void* d_ws, size_t ws_size,
                              hipStream_t stream) {
    const float* x = (const float*)d_in[0];
    float* out = (float*)d_out;
    char* ws = (char*)d_ws;
    // workspace layout (~6.0 MB; all regions written before read each call):
    //   idx_buf: 16*50*1536 u8                       = 1,228,800 B @ 0
    //   Abuf:    16*32*1536 f16                      = 1,572,864 B @ 1,228,800
    //   Xp:      16 chunks * 16*768 complex double   = 3,145,728 B @ 2,801,664
    //   Xf:      16*768 float2                       =    98,304 B @ 5,947,392
    unsigned char* idx_buf = (unsigned char*)ws;
    _Float16* Abuf = (_Float16*)(ws + 1228800);
    double* Xp = (double*)(ws + 2801664);
    float2* Xf = (float2*)(ws + 5947392);

    dft_kernel<<<dim3(NBC, FMAX / 256, NCH), 256, 0, stream>>>(x, Xp);
    reduce_kernel<<<NBC * FMAX / 256, 256, 0, stream>>>(Xp, Xf);
    band_kernel<<<dim3(NBC, TT / TW), TPB, 0, stream>>>(Xf, idx_buf, Abuf);
    mi_kernel<<<NBC * PHA_N, 256, 0, stream>>>(idx_buf, Abuf, out);
}

// Round 17
// 104.281 us; speedup vs baseline: 1.2652x; 1.2652x over previous
//
#include <hip/hip_runtime.h>
#include <hip/hip_bf16.h>
#include <math.h>

#ifndef M_PI
#define M_PI 3.14159265358979323846
#endif

#define T 2048
#define EDGE 256
#define TT 1536            // trimmed timesteps
#define PHA_N 50
#define AMP_N 30
#define NBANDS 80
#define NBINS 18
#define NBC 16             // B*C = 2*8
#define FMAX 768           // forward DFT bins stored [0, FMAX); max needed bin = 634
#define NCH 16             // t-chunks for forward DFT
#define CHLEN (T / NCH)    // 128
#define BK 640             // padded K for band GEMM (g = 1..640 covers fh<=634)
#define BWAVES 4
#define KPW (BK / BWAVES)  // 160 k per wave -> 10 K-steps of 16

typedef __attribute__((ext_vector_type(8))) short short8;       // 8x16-bit
typedef __attribute__((ext_vector_type(8))) _Float16 half8;     // 8 f16 (4 VGPRs)
typedef __attribute__((ext_vector_type(16))) float float16;     // 32x32 C/D frag

// Inclusive frequency-bin range [fl, fh] for a band, replicating the
// reference's float32 band edges vs exact quarter-Hz freq grid.
__device__ __forceinline__ void band_range(int band, int* fl, int* fh) {
    double lo, hi;
    if (band < PHA_N) {
        double mid = 2.0 + (double)band * (18.0 / 49.0);   // linspace(2,20,50)
        lo = (double)(float)(mid * 0.75);
        hi = (double)(float)(mid * 1.25);
    } else {
        int j = band - PHA_N;
        double mid = 60.0 + (double)j * (81.0 / 29.0);     // linspace(60,141,30)
        lo = (double)(float)(mid * 0.875);
        hi = (double)(float)(mid * 1.125);
    }
    int l = (int)ceil(lo * 4.0);     // freq = 0.25*f ; f >= 4*lo
    int h = (int)floor(hi * 4.0);    // f <= 4*hi
    if (l < 1) l = 1;
    if (h > FMAX - 1) h = FMAX - 1;
    *fl = l; *fh = h;
}

// Kernel A: chunked forward DFT partials (fp64). Two independent 64-step
// oscillator chains per thread; Xp layout ch-slowest for coalesced writes.
__global__ void dft_kernel(const float* __restrict__ x, double* __restrict__ Xp) {
    __shared__ float xs[CHLEN];
    const int bc = blockIdx.x;
    const int fb = blockIdx.y;
    const int ch = blockIdx.z;
    const int tid = threadIdx.x;
    const int t0 = ch * CHLEN;
    if (tid < CHLEN) xs[tid] = x[bc * T + t0 + tid];
    __syncthreads();
    const int f = fb * 256 + tid;
    const double om = 2.0 * M_PI / (double)T;
    double s, c;
    sincos(om * (double)(f & (T - 1)), &s, &c);
    const double wR = c, wI = -s;                       // e^{-i om f}
    double curR[2], curI[2], accR[2], accI[2];
    #pragma unroll
    for (int h = 0; h < 2; ++h) {
        sincos(om * (double)((f * (t0 + h * 64)) & (T - 1)), &s, &c);
        curR[h] = c; curI[h] = -s;                      // e^{-i om f (t0+64h)}
        accR[h] = 0.0; accI[h] = 0.0;
    }
    #pragma unroll 2
    for (int t = 0; t < 64; ++t) {
        #pragma unroll
        for (int h = 0; h < 2; ++h) {
            double v = (double)xs[t + h * 64];
            accR[h] += v * curR[h];
            accI[h] += v * curI[h];
            double nR = curR[h] * wR - curI[h] * wI;
            double nI = curR[h] * wI + curI[h] * wR;
            curR[h] = nR; curI[h] = nI;
        }
    }
    const size_t o = (size_t)((ch * NBC + bc) * FMAX + f) * 2;
    Xp[o + 0] = accR[0] + accR[1];
    Xp[o + 1] = accI[0] + accI[1];
}

// Kernel A2: reduce NCH chunk partials -> float2 Xf[bc*FMAX+f].
__global__ void reduce_kernel(const double* __restrict__ Xp, float2* __restrict__ Xf) {
    const int gid = blockIdx.x * 256 + threadIdx.x;   // 0..12287 = bc*FMAX+f
    double r = 0.0, im = 0.0;
    #pragma unroll
    for (int c = 0; c < NCH; ++c) {
        r  += Xp[((size_t)c * NBC * FMAX + gid) * 2 + 0];
        im += Xp[((size_t)c * NBC * FMAX + gid) * 2 + 1];
    }
    Xf[gid] = make_float2((float)r, (float)im);
}

// Kernel B (R16 restructure): band synthesis as MASKED GEMM on the matrix pipe.
//   S[band][t] = sum_k Mask[band][k] * Z[k][t],  Z[k][t] = X[g] e^{i om g t}, g=k+1
// Block = (bc, 32 t's); 4 waves = K-quarters (160 k, 10 K-steps of 16);
// 3 M-tiles cover 96 rows (bands 0..79 + dead). A-frags (0/1 mask) and B-frags
// (Z, f16) built in registers; layouts validated by mi_kernel (R10-R12).
// Re and Im accumulate in separate MFMAs sharing the B oscillator work.
// Precision: f16 Z -> rel err 2.4e-4 on S, NO cancellation (direct masked sum).
__global__ __launch_bounds__(256, 3)
void band_kernel(const float2* __restrict__ Xf,
                 unsigned char* __restrict__ idx_buf,
                 _Float16* __restrict__ Abuf) {
    __shared__ float uni[2560];              // K-loop: sXr=uni[k], sXi=uni[1280+k]; epilogue: Sre[80][32]
    __shared__ float cpart[BWAVES][2560];    // 40 KB: per-wave C partials (re pass, then im pass)
    __shared__ int bfl_s[96], bfh_s[96];
    const int bc = blockIdx.x;
    const int tg = blockIdx.y;               // 48 groups of 32 t
    const int tid = threadIdx.x;
    const int wave = tid >> 6, lane = tid & 63;
    const int n = lane & 31;                 // C col (t), A row-in-tile (band)
    const int kq = lane >> 5;                // k-quad within K-step
    const int t = tg * 32 + n + EDGE;        // absolute time

    for (int i = tid; i < BK; i += 256) {    // stage X for g = i+1
        const float2 v = Xf[bc * FMAX + i + 1];
        uni[i] = v.x; uni[1280 + i] = v.y;
    }
    if (tid < 96) {
        int fl = 1, fh = 0;                  // empty mask for dead bands 80..95
        if (tid < NBANDS) band_range(tid, &fl, &fh);
        bfl_s[tid] = fl; bfh_s[tid] = fh;
    }
    __syncthreads();

    const int fl0 = bfl_s[n],      fh0 = bfh_s[n];
    const int fl1 = bfl_s[32 + n], fh1 = bfh_s[32 + n];
    const int fl2 = bfl_s[64 + n], fh2 = bfh_s[64 + n];

    // oscillator constants (per lane): step = e^{i om t}, R16 = step^16
    const float omf = (float)(2.0 * M_PI / (double)T);
    float sw, cw;
    sincosf(omf * (float)(t & (T - 1)), &sw, &cw);
    float r16c = cw, r16s = sw;
    #pragma unroll
    for (int q = 0; q < 4; ++q) {            // 4 squarings -> step^16
        const float nc = r16c * r16c - r16s * r16s;
        const float ns = 2.0f * r16c * r16s;
        r16c = nc; r16s = ns;
    }
    const int Koff = wave * KPW;
    const int gg0 = 1 + Koff + kq * 8;       // g of j=0 at ks=0
    float cur0c, cur0s;
    { float s0, c0; sincosf(omf * (float)((gg0 * t) & (T - 1)), &s0, &c0);
      cur0c = c0; cur0s = s0; }              // e^{i om gg0 t}

    float16 aR0 = {0.0f}, aR1 = {0.0f}, aR2 = {0.0f};
    float16 aI0 = {0.0f}, aI1 = {0.0f}, aI2 = {0.0f};
    for (int ks = 0; ks < 10; ++ks) {
        const int kbase = Koff + kq * 8 + ks * 16;   // k of j=0
        float cc = cur0c, cs = cur0s;
        half8 bre, bim;
        #pragma unroll
        for (int j = 0; j < 8; ++j) {
            const float Xr = uni[kbase + j];          // broadcast (uniform/half-wave)
            const float Xi = uni[1280 + kbase + j];
            bre[j] = (_Float16)(Xr * cc - Xi * cs);
            bim[j] = (_Float16)(Xr * cs + Xi * cc);
            const float nc = cc * cw - cs * sw;       // rotate by step
            const float ns = cc * sw + cs * cw;
            cc = nc; cs = ns;
        }
        { const float nc = cur0c * r16c - cur0s * r16s;   // advance frag base
          const float ns = cur0c * r16s + cur0s * r16c;
          cur0c = nc; cur0s = ns; }
        short8 a0s, a1s, a2s;
        #pragma unroll
        for (int j = 0; j < 8; ++j) {
            const int g = kbase + j + 1;
            a0s[j] = (g >= fl0 && g <= fh0) ? (short)0x3C00 : (short)0;
            a1s[j] = (g >= fl1 && g <= fh1) ? (short)0x3C00 : (short)0;
            a2s[j] = (g >= fl2 && g <= fh2) ? (short)0x3C00 : (short)0;
        }
        const half8 a0 = __builtin_bit_cast(half8, a0s);
        const half8 a1 = __builtin_bit_cast(half8, a1s);
        const half8 a2 = __builtin_bit_cast(half8, a2s);
        aR0 = __builtin_amdgcn_mfma_f32_32x32x16_f16(a0, bre, aR0, 0, 0, 0);
        aI0 = __builtin_amdgcn_mfma_f32_32x32x16_f16(a0, bim, aI0, 0, 0, 0);
        aR1 = __builtin_amdgcn_mfma_f32_32x32x16_f16(a1, bre, aR1, 0, 0, 0);
        aI1 = __builtin_amdgcn_mfma_f32_32x32x16_f16(a1, bim, aI1, 0, 0, 0);
        aR2 = __builtin_amdgcn_mfma_f32_32x32x16_f16(a2, bre, aR2, 0, 0, 0);
        aI2 = __builtin_amdgcn_mfma_f32_32x32x16_f16(a2, bim, aI2, 0, 0, 0);
    }
    __syncthreads();   // K-loop LDS reads done; uni may be reused

    // pass 1: Re partials -> cpart, reduce into uni (Sre[band*32+n])
    #pragma unroll
    for (int r = 0; r < 16; ++r) {
        const int row = (r & 3) + 8 * (r >> 2) + 4 * kq;    // verified C layout
        cpart[wave][row * 32 + n] = aR0[r];
        cpart[wave][(32 + row) * 32 + n] = aR1[r];
        if (row < 16) cpart[wave][(64 + row) * 32 + n] = aR2[r];
    }
    __syncthreads();
    for (int i = tid; i < 2560; i += 256)
        uni[i] = cpart[0][i] + cpart[1][i] + cpart[2][i] + cpart[3][i];
    __syncthreads();
    // pass 2: Im partials -> cpart
    #pragma unroll
    for (int r = 0; r < 16; ++r) {
        const int row = (r & 3) + 8 * (r >> 2) + 4 * kq;
        cpart[wave][row * 32 + n] = aI0[r];
        cpart[wave][(32 + row) * 32 + n] = aI1[r];
        if (row < 16) cpart[wave][(64 + row) * 32 + n] = aI2[r];
    }
    __syncthreads();

    const float widthf = (float)(2.0 * M_PI / (double)NBINS);
    const float pif = (float)M_PI;
    for (int i = tid; i < 2560; i += 256) {
        const int band = i >> 5, nn = i & 31;
        const float Sre = uni[i];
        const float Sim = cpart[0][i] + cpart[1][i] + cpart[2][i] + cpart[3][i];
        const int trel = tg * 32 + nn;
        if (band < PHA_N) {
            float pha = atan2f(Sim, Sre);                   // (-pi, pi]
            int b = (int)floorf((pha + pif) / widthf);
            if (b < 0) b = 0;
            if (b > NBINS - 1) b = NBINS - 1;
            idx_buf[(size_t)(bc * PHA_N + band) * TT + trel] = (unsigned char)b;
        } else {
            float amp = sqrtf(Sre * Sre + Sim * Sim) * (2.0f / (float)T);
            Abuf[(size_t)(bc * 32 + (band - PHA_N)) * TT + trel] = (_Float16)amp;
        }
    }
    if (tid < 32)   // ones (counts) row
        Abuf[(size_t)(bc * 32 + 30) * TT + tg * 32 + tid] = (_Float16)1.0f;
}

// Kernel C: bin-sum as f16 MFMA matmul + inline MI epilogue (frozen since R12).
// Per (bc,p) block: C[31x18] = A[31x1536](f16 amp+ones) x Onehot[1536x18].
__global__ void mi_kernel(const unsigned char* __restrict__ idx_buf,
                          const _Float16* __restrict__ Abuf,
                          float* __restrict__ out) {
    __shared__ unsigned int sidx_s[TT / 4];       // 384 packed idx words
    __shared__ float cpart[4][32][NBINS];         // per-kquarter C partials
    const int blk = blockIdx.x;                   // bc*50 + p
    const int bc = blk / PHA_N;
    const int p = blk % PHA_N;
    const int tid = threadIdx.x;
    const int wave = tid >> 6;                    // k-quarter 0..3
    const int lane = tid & 63;

    for (int i = tid; i < TT / 4; i += 256)
        sidx_s[i] = ((const unsigned int*)(idx_buf + (size_t)(bc * PHA_N + p) * TT))[i];
    __syncthreads();

    const int n = lane & 31;                      // A row m == B col n == lane&31
    const int kq = lane >> 5;                     // k-quad: 0 or 1 (8 k's each)
    const half8* arow = (const half8*)(Abuf + (size_t)(bc * 32 + n) * TT
                                       + wave * 384 + kq * 8);
    float16 acc = {0.0f};
    #pragma unroll 4
    for (int ks = 0; ks < 24; ++ks) {
        const half8 a = arow[ks * 2];             // K-step stride = 16 f16 = 2 half8
        const int w0 = wave * 96 + ks * 4 + kq * 2;
        const unsigned int lo = sidx_s[w0];
        const unsigned int hi = sidx_s[w0 + 1];
        short8 bs;
        bs[0] = ((lo & 0xffu) == (unsigned)n) ? (short)0x3C00 : (short)0;   // f16 1.0
        bs[1] = (((lo >> 8) & 0xffu) == (unsigned)n) ? (short)0x3C00 : (short)0;
        bs[2] = (((lo >> 16) & 0xffu) == (unsigned)n) ? (short)0x3C00 : (short)0;
        bs[3] = ((lo >> 24) == (unsigned)n) ? (short)0x3C00 : (short)0;
        bs[4] = ((hi & 0xffu) == (unsigned)n) ? (short)0x3C00 : (short)0;
        bs[5] = (((hi >> 8) & 0xffu) == (unsigned)n) ? (short)0x3C00 : (short)0;
        bs[6] = (((hi >> 16) & 0xffu) == (unsigned)n) ? (short)0x3C00 : (short)0;
        bs[7] = ((hi >> 24) == (unsigned)n) ? (short)0x3C00 : (short)0;
        const half8 b = __builtin_bit_cast(half8, bs);
        acc = __builtin_amdgcn_mfma_f32_32x32x16_f16(a, b, acc, 0, 0, 0);
    }

    // scatter C frag to LDS (cols >= NBINS and row 31 discarded)
    if (n < NBINS) {
        #pragma unroll
        for (int r = 0; r < 16; ++r) {
            const int row = (r & 3) + 8 * (r >> 2) + 4 * kq;
            if (row < 31) cpart[wave][row][n] = acc[r];
        }
    }
    __syncthreads();

    // MI epilogue: thread a < 30 computes out[blk*30 + a]
    if (tid < AMP_N) {
        const int a = tid;
        double m[NBINS], tot = 0.0;
        #pragma unroll
        for (int k = 0; k < NBINS; ++k) {
            double cnt = (double)(cpart[0][30][k] + cpart[1][30][k]
                                + cpart[2][30][k] + cpart[3][30][k]);     // counts
            double denom = cnt > 1e-9 ? cnt : 1e-9;
            double s = (double)(cpart[0][a][k] + cpart[1][a][k]
                              + cpart[2][a][k] + cpart[3][a][k]);
            m[k] = s / denom;
            tot += m[k];
        }
        double dt = tot > 1e-9 ? tot : 1e-9;
        double accm = 0.0;
        #pragma unroll
        for (int k = 0; k < NBINS; ++k) {
            double pr = m[k] / dt;
            accm += pr * log(pr + 1e-9);
        }
        const double lognb = log((double)NBINS);
        out[(size_t)blk * AMP_N + a] = (float)((lognb + accm) / lognb);
    }
}

extern "C" void kernel_launch(void* const* d_in, const int* in_sizes, int n_in,
                              void* d_out, int out_size, void* d_ws, size_t ws_size,
                              hipStream_t stream) {
    const float* x = (const float*)d_in[0];
    float* out = (float*)d_out;
    char* ws = (char*)d_ws;
    // workspace layout (~6.0 MB; all regions written before read each call):
    //   idx_buf: 16*50*1536 u8                       = 1,228,800 B @ 0
    //   Abuf:    16*32*1536 f16                      = 1,572,864 B @ 1,228,800
    //   Xp:      16 chunks * 16*768 complex double   = 3,145,728 B @ 2,801,664
    //   Xf:      16*768 float2                       =    98,304 B @ 5,947,392
    unsigned char* idx_buf = (unsigned char*)ws;
    _Float16* Abuf = (_Float16*)(ws + 1228800);
    double* Xp = (double*)(ws + 2801664);
    float2* Xf = (float2*)(ws + 5947392);

    dft_kernel<<<dim3(NBC, FMAX / 256, NCH), 256, 0, stream>>>(x, Xp);
    reduce_kernel<<<NBC * FMAX / 256, 256, 0, stream>>>(Xp, Xf);
    band_kernel<<<dim3(NBC, TT / 32), 256, 0, stream>>>(Xf, idx_buf, Abuf);
    mi_kernel<<<NBC * PHA_N, 256, 0, stream>>>(idx_buf, Abuf, out);
}

// Round 18
// 98.044 us; speedup vs baseline: 1.3457x; 1.0636x over previous
//
#include <hip/hip_runtime.h>
#include <hip/hip_bf16.h>
#include <math.h>

#ifndef M_PI
#define M_PI 3.14159265358979323846
#endif

#define T 2048
#define EDGE 256
#define TT 1536            // trimmed timesteps
#define PHA_N 50
#define AMP_N 30
#define NBANDS 80
#define NBINS 18
#define NBC 16             // B*C = 2*8
#define FMAX 768           // forward DFT bins stored [0, FMAX); max needed bin = 634
#define NCH 16             // t-chunks for forward DFT
#define CHLEN (T / NCH)    // 128
#define BK 640             // padded K for band GEMM (g = 1..640 covers fh<=634)
#define BWAVES 4
#define KPW (BK / BWAVES)  // 160 k per wave -> 10 K-steps of 16

typedef __attribute__((ext_vector_type(8))) short short8;       // 8x16-bit
typedef __attribute__((ext_vector_type(8))) _Float16 half8;     // 8 f16 (4 VGPRs)
typedef __attribute__((ext_vector_type(16))) float float16;     // 32x32 C/D frag

// Inclusive frequency-bin range [fl, fh] for a band, replicating the
// reference's float32 band edges vs exact quarter-Hz freq grid.
__device__ __forceinline__ void band_range(int band, int* fl, int* fh) {
    double lo, hi;
    if (band < PHA_N) {
        double mid = 2.0 + (double)band * (18.0 / 49.0);   // linspace(2,20,50)
        lo = (double)(float)(mid * 0.75);
        hi = (double)(float)(mid * 1.25);
    } else {
        int j = band - PHA_N;
        double mid = 60.0 + (double)j * (81.0 / 29.0);     // linspace(60,141,30)
        lo = (double)(float)(mid * 0.875);
        hi = (double)(float)(mid * 1.125);
    }
    int l = (int)ceil(lo * 4.0);     // freq = 0.25*f ; f >= 4*lo
    int h = (int)floor(hi * 4.0);    // f <= 4*hi
    if (l < 1) l = 1;
    if (h > FMAX - 1) h = FMAX - 1;
    *fl = l; *fh = h;
}

// Kernel A (R17: fp32 — downstream error budget is f16 2.4e-4; fp32 adds
// ~2e-6 rel). Chunked forward DFT partials; two independent 64-step chains.
__global__ void dft_kernel(const float* __restrict__ x, float2* __restrict__ Xp) {
    __shared__ float xs[CHLEN];
    const int bc = blockIdx.x;
    const int fb = blockIdx.y;
    const int ch = blockIdx.z;
    const int tid = threadIdx.x;
    const int t0 = ch * CHLEN;
    if (tid < CHLEN) xs[tid] = x[bc * T + t0 + tid];
    __syncthreads();
    const int f = fb * 256 + tid;
    const float omf = (float)(2.0 * M_PI / (double)T);
    float s, c;
    sincosf(omf * (float)(f & (T - 1)), &s, &c);
    const float wR = c, wI = -s;                        // e^{-i om f}
    float curR[2], curI[2], accR[2], accI[2];
    #pragma unroll
    for (int h = 0; h < 2; ++h) {
        sincosf(omf * (float)((f * (t0 + h * 64)) & (T - 1)), &s, &c);
        curR[h] = c; curI[h] = -s;                      // e^{-i om f (t0+64h)}
        accR[h] = 0.0f; accI[h] = 0.0f;
    }
    #pragma unroll 2
    for (int t = 0; t < 64; ++t) {
        #pragma unroll
        for (int h = 0; h < 2; ++h) {
            const float v = xs[t + h * 64];
            accR[h] += v * curR[h];
            accI[h] += v * curI[h];
            const float nR = curR[h] * wR - curI[h] * wI;
            const float nI = curR[h] * wI + curI[h] * wR;
            curR[h] = nR; curI[h] = nI;
        }
    }
    Xp[(size_t)((ch * NBC + bc) * FMAX + f)] =
        make_float2(accR[0] + accR[1], accI[0] + accI[1]);
}

// Kernel A2: reduce NCH chunk partials -> float2 Xf[bc*FMAX+f].
__global__ void reduce_kernel(const float2* __restrict__ Xp, float2* __restrict__ Xf) {
    const int gid = blockIdx.x * 256 + threadIdx.x;   // 0..12287 = bc*FMAX+f
    float r = 0.0f, im = 0.0f;
    #pragma unroll
    for (int c = 0; c < NCH; ++c) {
        const float2 v = Xp[(size_t)c * NBC * FMAX + gid];
        r += v.x; im += v.y;
    }
    Xf[gid] = make_float2(r, im);
}

// Kernel B (frozen R16): band synthesis as MASKED GEMM on the matrix pipe.
//   S[band][t] = sum_k Mask[band][k] * Z[k][t],  Z[k][t] = X[g] e^{i om g t}, g=k+1
// Block = (bc, 32 t's); 4 waves = K-quarters; 3 M-tiles cover 96 rows.
// A-frags (0/1 mask) and B-frags (Z, f16) built in registers (layouts
// validated R10-R12). Re/Im accumulate in separate MFMAs sharing B-osc work.
__global__ __launch_bounds__(256, 3)
void band_kernel(const float2* __restrict__ Xf,
                 unsigned char* __restrict__ idx_buf,
                 _Float16* __restrict__ Abuf) {
    __shared__ float uni[2560];              // K-loop: sXr=uni[k], sXi=uni[1280+k]; epilogue: Sre[80][32]
    __shared__ float cpart[BWAVES][2560];    // 40 KB: per-wave C partials (re pass, then im pass)
    __shared__ int bfl_s[96], bfh_s[96];
    const int bc = blockIdx.x;
    const int tg = blockIdx.y;               // 48 groups of 32 t
    const int tid = threadIdx.x;
    const int wave = tid >> 6, lane = tid & 63;
    const int n = lane & 31;                 // C col (t), A row-in-tile (band)
    const int kq = lane >> 5;                // k-quad within K-step
    const int t = tg * 32 + n + EDGE;        // absolute time

    for (int i = tid; i < BK; i += 256) {    // stage X for g = i+1
        const float2 v = Xf[bc * FMAX + i + 1];
        uni[i] = v.x; uni[1280 + i] = v.y;
    }
    if (tid < 96) {
        int fl = 1, fh = 0;                  // empty mask for dead bands 80..95
        if (tid < NBANDS) band_range(tid, &fl, &fh);
        bfl_s[tid] = fl; bfh_s[tid] = fh;
    }
    __syncthreads();

    const int fl0 = bfl_s[n],      fh0 = bfh_s[n];
    const int fl1 = bfl_s[32 + n], fh1 = bfh_s[32 + n];
    const int fl2 = bfl_s[64 + n], fh2 = bfh_s[64 + n];

    // oscillator constants (per lane): step = e^{i om t}, R16 = step^16
    const float omf = (float)(2.0 * M_PI / (double)T);
    float sw, cw;
    sincosf(omf * (float)(t & (T - 1)), &sw, &cw);
    float r16c = cw, r16s = sw;
    #pragma unroll
    for (int q = 0; q < 4; ++q) {            // 4 squarings -> step^16
        const float nc = r16c * r16c - r16s * r16s;
        const float ns = 2.0f * r16c * r16s;
        r16c = nc; r16s = ns;
    }
    const int Koff = wave * KPW;
    const int gg0 = 1 + Koff + kq * 8;       // g of j=0 at ks=0
    float cur0c, cur0s;
    { float s0, c0; sincosf(omf * (float)((gg0 * t) & (T - 1)), &s0, &c0);
      cur0c = c0; cur0s = s0; }              // e^{i om gg0 t}

    float16 aR0 = {0.0f}, aR1 = {0.0f}, aR2 = {0.0f};
    float16 aI0 = {0.0f}, aI1 = {0.0f}, aI2 = {0.0f};
    for (int ks = 0; ks < 10; ++ks) {
        const int kbase = Koff + kq * 8 + ks * 16;   // k of j=0
        float cc = cur0c, cs = cur0s;
        half8 bre, bim;
        #pragma unroll
        for (int j = 0; j < 8; ++j) {
            const float Xr = uni[kbase + j];          // broadcast (half-wave uniform)
            const float Xi = uni[1280 + kbase + j];
            bre[j] = (_Float16)(Xr * cc - Xi * cs);
            bim[j] = (_Float16)(Xr * cs + Xi * cc);
            const float nc = cc * cw - cs * sw;       // rotate by step
            const float ns = cc * sw + cs * cw;
            cc = nc; cs = ns;
        }
        { const float nc = cur0c * r16c - cur0s * r16s;   // advance frag base
          const float ns = cur0c * r16s + cur0s * r16c;
          cur0c = nc; cur0s = ns; }
        short8 a0s, a1s, a2s;
        #pragma unroll
        for (int j = 0; j < 8; ++j) {
            const int g = kbase + j + 1;
            a0s[j] = (g >= fl0 && g <= fh0) ? (short)0x3C00 : (short)0;
            a1s[j] = (g >= fl1 && g <= fh1) ? (short)0x3C00 : (short)0;
            a2s[j] = (g >= fl2 && g <= fh2) ? (short)0x3C00 : (short)0;
        }
        const half8 a0 = __builtin_bit_cast(half8, a0s);
        const half8 a1 = __builtin_bit_cast(half8, a1s);
        const half8 a2 = __builtin_bit_cast(half8, a2s);
        aR0 = __builtin_amdgcn_mfma_f32_32x32x16_f16(a0, bre, aR0, 0, 0, 0);
        aI0 = __builtin_amdgcn_mfma_f32_32x32x16_f16(a0, bim, aI0, 0, 0, 0);
        aR1 = __builtin_amdgcn_mfma_f32_32x32x16_f16(a1, bre, aR1, 0, 0, 0);
        aI1 = __builtin_amdgcn_mfma_f32_32x32x16_f16(a1, bim, aI1, 0, 0, 0);
        aR2 = __builtin_amdgcn_mfma_f32_32x32x16_f16(a2, bre, aR2, 0, 0, 0);
        aI2 = __builtin_amdgcn_mfma_f32_32x32x16_f16(a2, bim, aI2, 0, 0, 0);
    }
    __syncthreads();   // K-loop LDS reads done; uni may be reused

    // pass 1: Re partials -> cpart, reduce into uni (Sre[band*32+n])
    #pragma unroll
    for (int r = 0; r < 16; ++r) {
        const int row = (r & 3) + 8 * (r >> 2) + 4 * kq;    // verified C layout
        cpart[wave][row * 32 + n] = aR0[r];
        cpart[wave][(32 + row) * 32 + n] = aR1[r];
        if (row < 16) cpart[wave][(64 + row) * 32 + n] = aR2[r];
    }
    __syncthreads();
    for (int i = tid; i < 2560; i += 256)
        uni[i] = cpart[0][i] + cpart[1][i] + cpart[2][i] + cpart[3][i];
    __syncthreads();
    // pass 2: Im partials -> cpart
    #pragma unroll
    for (int r = 0; r < 16; ++r) {
        const int row = (r & 3) + 8 * (r >> 2) + 4 * kq;
        cpart[wave][row * 32 + n] = aI0[r];
        cpart[wave][(32 + row) * 32 + n] = aI1[r];
        if (row < 16) cpart[wave][(64 + row) * 32 + n] = aI2[r];
    }
    __syncthreads();

    const float widthf = (float)(2.0 * M_PI / (double)NBINS);
    const float pif = (float)M_PI;
    for (int i = tid; i < 2560; i += 256) {
        const int band = i >> 5, nn = i & 31;
        const float Sre = uni[i];
        const float Sim = cpart[0][i] + cpart[1][i] + cpart[2][i] + cpart[3][i];
        const int trel = tg * 32 + nn;
        if (band < PHA_N) {
            float pha = atan2f(Sim, Sre);                   // (-pi, pi]
            int b = (int)floorf((pha + pif) / widthf);
            if (b < 0) b = 0;
            if (b > NBINS - 1) b = NBINS - 1;
            idx_buf[(size_t)(bc * PHA_N + band) * TT + trel] = (unsigned char)b;
        } else {
            float amp = sqrtf(Sre * Sre + Sim * Sim) * (2.0f / (float)T);
            Abuf[(size_t)(bc * 32 + (band - PHA_N)) * TT + trel] = (_Float16)amp;
        }
    }
    if (tid < 32)   // ones (counts) row
        Abuf[(size_t)(bc * 32 + 30) * TT + tg * 32 + tid] = (_Float16)1.0f;
}

// Kernel C: bin-sum as f16 MFMA matmul + inline MI epilogue (core frozen
// since R12; R17: epilogue fp32/logf — err ~1e-7, kills the fp64-log tail).
__global__ void mi_kernel(const unsigned char* __restrict__ idx_buf,
                          const _Float16* __restrict__ Abuf,
                          float* __restrict__ out) {
    __shared__ unsigned int sidx_s[TT / 4];       // 384 packed idx words
    __shared__ float cpart[4][32][NBINS];         // per-kquarter C partials
    const int blk = blockIdx.x;                   // bc*50 + p
    const int bc = blk / PHA_N;
    const int p = blk % PHA_N;
    const int tid = threadIdx.x;
    const int wave = tid >> 6;                    // k-quarter 0..3
    const int lane = tid & 63;

    for (int i = tid; i < TT / 4; i += 256)
        sidx_s[i] = ((const unsigned int*)(idx_buf + (size_t)(bc * PHA_N + p) * TT))[i];
    __syncthreads();

    const int n = lane & 31;                      // A row m == B col n == lane&31
    const int kq = lane >> 5;                     // k-quad: 0 or 1 (8 k's each)
    const half8* arow = (const half8*)(Abuf + (size_t)(bc * 32 + n) * TT
                                       + wave * 384 + kq * 8);
    float16 acc = {0.0f};
    #pragma unroll 4
    for (int ks = 0; ks < 24; ++ks) {
        const half8 a = arow[ks * 2];             // K-step stride = 16 f16 = 2 half8
        const int w0 = wave * 96 + ks * 4 + kq * 2;
        const unsigned int lo = sidx_s[w0];
        const unsigned int hi = sidx_s[w0 + 1];
        short8 bs;
        bs[0] = ((lo & 0xffu) == (unsigned)n) ? (short)0x3C00 : (short)0;   // f16 1.0
        bs[1] = (((lo >> 8) & 0xffu) == (unsigned)n) ? (short)0x3C00 : (short)0;
        bs[2] = (((lo >> 16) & 0xffu) == (unsigned)n) ? (short)0x3C00 : (short)0;
        bs[3] = ((lo >> 24) == (unsigned)n) ? (short)0x3C00 : (short)0;
        bs[4] = ((hi & 0xffu) == (unsigned)n) ? (short)0x3C00 : (short)0;
        bs[5] = (((hi >> 8) & 0xffu) == (unsigned)n) ? (short)0x3C00 : (short)0;
        bs[6] = (((hi >> 16) & 0xffu) == (unsigned)n) ? (short)0x3C00 : (short)0;
        bs[7] = ((hi >> 24) == (unsigned)n) ? (short)0x3C00 : (short)0;
        const half8 b = __builtin_bit_cast(half8, bs);
        acc = __builtin_amdgcn_mfma_f32_32x32x16_f16(a, b, acc, 0, 0, 0);
    }

    // scatter C frag to LDS (cols >= NBINS and row 31 discarded)
    if (n < NBINS) {
        #pragma unroll
        for (int r = 0; r < 16; ++r) {
            const int row = (r & 3) + 8 * (r >> 2) + 4 * kq;
            if (row < 31) cpart[wave][row][n] = acc[r];
        }
    }
    __syncthreads();

    // MI epilogue (fp32): thread a < 30 computes out[blk*30 + a]
    if (tid < AMP_N) {
        const int a = tid;
        float m[NBINS], tot = 0.0f;
        #pragma unroll
        for (int k = 0; k < NBINS; ++k) {
            const float cnt = cpart[0][30][k] + cpart[1][30][k]
                            + cpart[2][30][k] + cpart[3][30][k];     // counts
            const float denom = cnt > 1e-9f ? cnt : 1e-9f;
            const float s = cpart[0][a][k] + cpart[1][a][k]
                          + cpart[2][a][k] + cpart[3][a][k];
            m[k] = s / denom;
            tot += m[k];
        }
        const float dt = tot > 1e-9f ? tot : 1e-9f;
        float accm = 0.0f;
        #pragma unroll
        for (int k = 0; k < NBINS; ++k) {
            const float pr = m[k] / dt;
            accm += pr * logf(pr + 1e-9f);
        }
        const float lognb = 2.8903717578961645f;   // ln(18)
        out[(size_t)blk * AMP_N + a] = (lognb + accm) / lognb;
    }
}

extern "C" void kernel_launch(void* const* d_in, const int* in_sizes, int n_in,
                              void* d_out, int out_size, void* d_ws, size_t ws_size,
                              hipStream_t stream) {
    const float* x = (const float*)d_in[0];
    float* out = (float*)d_out;
    char* ws = (char*)d_ws;
    // workspace layout (~4.5 MB; all regions written before read each call):
    //   idx_buf: 16*50*1536 u8                       = 1,228,800 B @ 0
    //   Abuf:    16*32*1536 f16                      = 1,572,864 B @ 1,228,800
    //   Xp:      16 chunks * 16*768 float2           = 1,572,864 B @ 2,801,664
    //   Xf:      16*768 float2                       =    98,304 B @ 4,374,528
    unsigned char* idx_buf = (unsigned char*)ws;
    _Float16* Abuf = (_Float16*)(ws + 1228800);
    float2* Xp = (float2*)(ws + 2801664);
    float2* Xf = (float2*)(ws + 4374528);

    dft_kernel<<<dim3(NBC, FMAX / 256, NCH), 256, 0, stream>>>(x, Xp);
    reduce_kernel<<<NBC * FMAX / 256, 256, 0, stream>>>(Xp, Xf);
    band_kernel<<<dim3(NBC, TT / 32), 256, 0, stream>>>(Xf, idx_buf, Abuf);
    mi_kernel<<<NBC * PHA_N, 256, 0, stream>>>(idx_buf, Abuf, out);
}